// Round 4
// baseline (210.254 us; speedup 1.0000x reference)
//
#include <hip/hip_runtime.h>
#include <hip/hip_bf16.h>
#include <math.h>

typedef __hip_bfloat16 bf16;
typedef __attribute__((ext_vector_type(8))) short short8;
typedef __attribute__((ext_vector_type(4))) float f32x4;
typedef __attribute__((ext_vector_type(4))) unsigned int u32x4;

#define MFMA16(A, B, C) __builtin_amdgcn_mfma_f32_16x16x32_bf16((A), (B), (C), 0, 0, 0)
#define NEG_BIG (-1e30f)
#define EXP2(x) __builtin_amdgcn_exp2f(x)
// 0.125 (1/sqrt(d_k)) * log2(e): folded into Q at projection time -> scores in log2 domain
#define QSCALE 0.18033688011112042f

// two-register half-swaps (gfx950): after P32SWAP(a,b): a=[a_lo,b_lo], b=[a_hi,b_hi]
// after P16SWAP(a,b): a=[a_r0,b_r0,a_r2,b_r2], b=[a_r1,b_r1,a_r3,b_r3] (16-lane rows)
#define P32SWAP(a, b) asm("v_permlane32_swap_b32 %0, %1" : "+v"(a), "+v"(b))
#define P16SWAP(a, b) asm("v_permlane16_swap_b32 %0, %1" : "+v"(a), "+v"(b))

static __device__ __forceinline__ unsigned int cvt_pk_bf16(float lo, float hi) {
    unsigned int r;
    asm("v_cvt_pk_bf16_f32 %0, %1, %2" : "=v"(r) : "v"(lo), "v"(hi));
    return r;
}

// fp32 -> bf16 round-to-nearest-even via bit ops
static __device__ __forceinline__ unsigned short f32_to_bf16_rne(float f) {
    unsigned int u = __float_as_uint(f);
    unsigned int rnd = 0x7FFFu + ((u >> 16) & 1u);
    return (unsigned short)((u + rnd) >> 16);
}

// In-kernel dtype detection (wave-uniform): scan first 64 shorts of x.
static __device__ __forceinline__ bool inputs_are_fp32(const unsigned short* x16) {
    int lane = threadIdx.x & 63;
    int e = (x16[lane] >> 7) & 0xFF;
    unsigned long long ball = __ballot(e >= 133);
    return __popcll(ball) >= 4;
}

// ---------------------------------------------------------------------------
// Kernel 0a: RoPE cos/sin table [s][p] float2, 2048 x 32 entries (512 KB).
// ---------------------------------------------------------------------------
__global__ __launch_bounds__(256) void rope_table(
    const int* __restrict__ pos, float2* __restrict__ tab)
{
    int i = blockIdx.x * 256 + threadIdx.x;   // 0..65535
    int s = i >> 5, p = i & 31;
    float freq = __expf((float)p * -0.28782313662425575f);
    float ang  = (float)pos[s] * freq;
    float sn, c;
    sincosf(ang, &sn, &c);
    tab[i] = make_float2(c, sn);
}

// ---------------------------------------------------------------------------
// Kernel 0b: canonical bf16 copies of all 5 inputs (fp32 path only).
// ---------------------------------------------------------------------------
__global__ __launch_bounds__(256) void convert_all(
    const void* __restrict__ xs, const void* __restrict__ wq,
    const void* __restrict__ wk, const void* __restrict__ wv,
    const void* __restrict__ wo,
    unsigned int* __restrict__ Xc, unsigned int* __restrict__ Wqc,
    unsigned int* __restrict__ Wkc, unsigned int* __restrict__ Wvc,
    unsigned int* __restrict__ Woc)
{
    if (!inputs_are_fp32((const unsigned short*)xs)) return;
    int i = blockIdx.x * 256 + threadIdx.x;  // 0 .. 4194303
    const float* src;
    unsigned int* dst;
    int off;
    if (i < 2097152) { src = (const float*)xs; dst = Xc; off = i; }
    else {
        int j = i - 2097152;
        int t = j >> 19;          // 0..3
        off = j & 524287;
        src = (const float*)((t == 0) ? wq : (t == 1) ? wk : (t == 2) ? wv : wo);
        dst = (t == 0) ? Wqc : (t == 1) ? Wkc : (t == 2) ? Wvc : Woc;
    }
    unsigned int lo = f32_to_bf16_rne(src[2 * off]);
    unsigned int hi = f32_to_bf16_rne(src[2 * off + 1]);
    dst[off] = (hi << 16) | lo;
}

// ---------------------------------------------------------------------------
// Kernel 1: QKV projection GEMM, 128x128 tile, BK=32.
// grid = (32 m-tiles, 24 = 3 weights x 8 n-tiles), block = 256 (2x2 waves).
// Q,K: RoPE-table epilogue [b,h,s,d]. V: LDS-transposed [b,h,d,s].
// Q pre-scaled by 0.125*log2(e) -> flash softmax in exp2 domain.
// ---------------------------------------------------------------------------
__global__ __launch_bounds__(256, 1) void gemm_qkv_rope(
    const void* __restrict__ xr,
    const void* __restrict__ wqr, const void* __restrict__ wkr,
    const void* __restrict__ wvr,
    const bf16* __restrict__ Xc,
    const bf16* __restrict__ Wqc, const bf16* __restrict__ Wkc,
    const bf16* __restrict__ Wvc,
    const float2* __restrict__ rtab,
    bf16* __restrict__ Qb, bf16* __restrict__ Kb, bf16* __restrict__ Vt)
{
    const bool f32in = inputs_are_fp32((const unsigned short*)xr);
    const bf16* X = f32in ? Xc : (const bf16*)xr;

    // union: staging (2 x 128x40) vs V-transpose tile (128x132)
    __shared__ __align__(16) short smem[128 * 132];   // 33792 B
    short* As = smem;              // [128][40]
    short* Bs = smem + 5120;       // [128][40]

    const int m0   = blockIdx.x * 128;
    const int wsel = blockIdx.y >> 3;            // 0=Q, 1=K, 2=V
    const int n0   = (blockIdx.y & 7) * 128;
    const bf16* W  = (wsel == 0) ? (f32in ? Wqc : (const bf16*)wqr)
                   : (wsel == 1) ? (f32in ? Wkc : (const bf16*)wkr)
                                 : (f32in ? Wvc : (const bf16*)wvr);

    const int tid  = threadIdx.x;
    const int lane = tid & 63;
    const int wave = tid >> 6;
    const int wr   = wave >> 1, wc = wave & 1;   // 2x2 waves, each 64x64
    const int m    = lane & 15;
    const int q    = lane >> 4;

    const int srow = tid >> 2;            // 0..63
    const int sseg = tid & 3;
    const bf16* Ag = X + (m0 + srow) * 1024 + sseg * 8;
    const bf16* Bg = W + (n0 + srow) * 1024 + sseg * 8;

    f32x4 acc[4][4];
    #pragma unroll
    for (int mi = 0; mi < 4; ++mi)
        #pragma unroll
        for (int ni = 0; ni < 4; ++ni)
            acc[mi][ni] = (f32x4){0.f, 0.f, 0.f, 0.f};

    short8 pa0 = *(const short8*)(Ag);
    short8 pa1 = *(const short8*)(Ag + 64 * 1024);
    short8 pb0 = *(const short8*)(Bg);
    short8 pb1 = *(const short8*)(Bg + 64 * 1024);

    for (int k0 = 0; k0 < 1024; k0 += 32) {
        __syncthreads();
        *(short8*)&As[srow * 40 + sseg * 8]        = pa0;
        *(short8*)&As[(srow + 64) * 40 + sseg * 8] = pa1;
        *(short8*)&Bs[srow * 40 + sseg * 8]        = pb0;
        *(short8*)&Bs[(srow + 64) * 40 + sseg * 8] = pb1;
        __syncthreads();
        if (k0 + 32 < 1024) {
            pa0 = *(const short8*)(Ag + k0 + 32);
            pa1 = *(const short8*)(Ag + 64 * 1024 + k0 + 32);
            pb0 = *(const short8*)(Bg + k0 + 32);
            pb1 = *(const short8*)(Bg + 64 * 1024 + k0 + 32);
        }

        short8 af[4], bfr[4];
        #pragma unroll
        for (int mi = 0; mi < 4; ++mi)
            af[mi] = *(const short8*)&As[(wr * 64 + mi * 16 + m) * 40 + q * 8];
        #pragma unroll
        for (int ni = 0; ni < 4; ++ni)
            bfr[ni] = *(const short8*)&Bs[(wc * 64 + ni * 16 + m) * 40 + q * 8];
        #pragma unroll
        for (int mi = 0; mi < 4; ++mi)
            #pragma unroll
            for (int ni = 0; ni < 4; ++ni)
                acc[mi][ni] = MFMA16(af[mi], bfr[ni], acc[mi][ni]);
    }

    const int bb  = m0 >> 11;
    const int s0  = m0 & 2047;
    const int hh0 = n0 >> 6;          // first of 2 heads in this n-tile

    if (wsel < 2) {
        bf16* dstb = (wsel == 0) ? Qb : Kb;
        const float sc = (wsel == 0) ? QSCALE : 1.0f;
        #pragma unroll
        for (int mi = 0; mi < 4; ++mi)
            #pragma unroll
            for (int ni = 0; ni < 4; ++ni)
                #pragma unroll
                for (int r = 0; r < 4; ++r) {
                    int s  = s0 + wr * 64 + mi * 16 + q * 4 + r;
                    int gn = n0 + wc * 64 + ni * 16 + m;
                    int hh = gn >> 6, d = gn & 63;
                    float v = acc[mi][ni][r];
                    float partner = __shfl_xor(v, 1);
                    float2 cs = rtab[s * 32 + (d >> 1)];
                    float outv = ((d & 1) == 0) ? (cs.x * v - cs.y * partner)
                                                : (cs.y * partner + cs.x * v);
                    dstb[((bb * 16 + hh) * 2048 + s) * 64 + d] =
                        __float2bfloat16(outv * sc);
                }
    } else {
        __syncthreads();   // all As/Bs reads done before alias overwrite
        #pragma unroll
        for (int mi = 0; mi < 4; ++mi)
            #pragma unroll
            for (int ni = 0; ni < 4; ++ni)
                #pragma unroll
                for (int r = 0; r < 4; ++r) {
                    int ls = wr * 64 + mi * 16 + q * 4 + r;   // local s 0..127
                    int ld = wc * 64 + ni * 16 + m;           // local d 0..127
                    bf16 hv = __float2bfloat16(acc[mi][ni][r]);
                    smem[ld * 132 + ls] = *(short*)&hv;
                }
        __syncthreads();
        int dd = tid >> 1;            // 0..127: head hh0 + (dd>>6), d = dd&63
        int half = tid & 1;
        bf16* vrow = Vt + ((bb * 16 + hh0 + (dd >> 6)) * 64 + (dd & 63)) * 2048
                        + s0 + half * 64;
        #pragma unroll
        for (int j = 0; j < 8; ++j)
            *(short8*)(vrow + j * 8) =
                *(const short8*)&smem[dd * 132 + half * 64 + j * 8];
    }
}

// ---------------------------------------------------------------------------
// Kernel 2: causal flash attention, K-SPLIT partial version.
// Round-3: each (qtile-pair) is split into 2 K-halves -> 1024 balanced
// blocks (8-9 iters each; ceil/floor pairing keeps totals equal), 4
// blocks/CU resident (LDS 35840*4=143KB, VGPR 92*16waves=368/SIMD-pool):
// 2x waves/SIMD and half the serial chain vs round-2.
// Each block emits UNNORMALIZED partial (O', m, l):
//   half 0 -> O' into its final ctx slot; half 1 -> Op1 scratch.
// flash_merge combines the two partials per (bh, qtile).
// ---------------------------------------------------------------------------
#define KST 72
#define VST 136

__global__ __launch_bounds__(256) void flash_attn(
    const bf16* __restrict__ Qb, const bf16* __restrict__ Kb,
    const bf16* __restrict__ Vt, bf16* __restrict__ ctx,
    bf16* __restrict__ Op1, float* __restrict__ Ml)
{
    const int pair = blockIdx.x >> 1;   // 0..15
    const int half = blockIdx.x & 1;    // 0..1 (K-range half)
    const int h = blockIdx.y, b = blockIdx.z;
    const int bh = b * 16 + h;

    __shared__ __align__(16) short Ks[128 * KST];
    __shared__ __align__(16) short Vs[64 * VST];

    const int tid  = threadIdx.x;
    const int lane = tid & 63;
    const int wave = tid >> 6;
    const int m = lane & 15;
    const int q = lane >> 4;

    const int krow = tid >> 1;
    const int kseg = (tid & 1) * 32;
    const int ksw  = ((krow >> 3) & 3) << 3;   // staging swizzle (shorts)
    const int vrow = tid >> 2;
    const int vseg = (tid & 3) * 32;

    const bf16* Kg = Kb + bh * 2048 * 64 + krow * 64   + kseg;
    const bf16* Vg = Vt + bh * 64 * 2048 + vrow * 2048 + vseg;

    for (int part = 0; part < 2; ++part) {
        const int qtile = (part == 0) ? pair : 31 - pair;
        const int nk2 = (qtile + 2) >> 1;
        // ceil/floor split alternates by part -> per-block totals 8 or 9
        const int mid = (part == 0) ? ((nk2 + 1) >> 1) : (nk2 >> 1);
        const int lo  = half ? mid : 0;
        const int hi  = half ? nk2 : mid;
        const int rowbase = qtile * 64 + wave * 16;

        const bf16* Qp = Qb + (bh * 2048 + rowbase + m) * 64;
        short8 qf0 = *(const short8*)(Qp + q * 8);
        short8 qf1 = *(const short8*)(Qp + 32 + q * 8);

        f32x4 oacc[4];
        #pragma unroll
        for (int nb = 0; nb < 4; ++nb) oacc[nb] = (f32x4){0.f, 0.f, 0.f, 0.f};
        float mi_s = NEG_BIG, li_s = 0.f;   // per-lane softmax row = rowbase + m

        short8 kr[4], vr[4];
        #pragma unroll
        for (int j = 0; j < 4; ++j) {
            kr[j] = *(const short8*)(Kg + lo * 8192 + j * 8);
            vr[j] = *(const short8*)(Vg + lo * 128  + j * 8);
        }

        for (int kt2 = lo; kt2 < hi; ++kt2) {
            __syncthreads();
            #pragma unroll
            for (int j = 0; j < 4; ++j) {
                *(short8*)&Ks[krow * KST + ((kseg + j * 8) ^ ksw)] = kr[j];
                *(short8*)&Vs[vrow * VST + vseg + j * 8] = vr[j];
            }
            __syncthreads();

            if (kt2 + 1 < hi) {
                #pragma unroll
                for (int j = 0; j < 4; ++j) {
                    kr[j] = *(const short8*)(Kg + (kt2 + 1) * 8192 + j * 8);
                    vr[j] = *(const short8*)(Vg + (kt2 + 1) * 128  + j * 8);
                }
            }

            // swapped QK^T: S[q-row = m][key = kt2*128 + nc*16 + q*4 + r]
            f32x4 sacc[8];
            #pragma unroll
            for (int nc = 0; nc < 8; ++nc) {
                int row = nc * 16 + m;
                int sw  = ((row >> 3) & 3) << 3;
                const short* kp = &Ks[row * KST];
                short8 kf0 = *(const short8*)&kp[(q * 8) ^ sw];
                short8 kf1 = *(const short8*)&kp[32 + ((q * 8) ^ sw)];
                f32x4 z = {0.f, 0.f, 0.f, 0.f};
                z = MFMA16(kf0, qf0, z);
                z = MFMA16(kf1, qf1, z);
                sacc[nc] = z;
            }

            // causal mask (log2-domain scores; scale folded into Q)
            if (kt2 * 128 + 127 > rowbase) {
                int rowg = rowbase + m;
                #pragma unroll
                for (int nc = 0; nc < 8; ++nc)
                    #pragma unroll
                    for (int r = 0; r < 4; ++r) {
                        int col = kt2 * 128 + nc * 16 + q * 4 + r;
                        if (col > rowg) sacc[nc][r] = NEG_BIG;
                    }
            }

            // in-lane tree max + cross-q butterfly (lanes m,q=0..3 share row m)
            float tm[8];
            #pragma unroll
            for (int nc = 0; nc < 8; ++nc)
                tm[nc] = fmaxf(fmaxf(sacc[nc][0], sacc[nc][1]),
                               fmaxf(sacc[nc][2], sacc[nc][3]));
            float rm = fmaxf(fmaxf(fmaxf(tm[0], tm[1]), fmaxf(tm[2], tm[3])),
                             fmaxf(fmaxf(tm[4], tm[5]), fmaxf(tm[6], tm[7])));
            rm = fmaxf(rm, __shfl_xor(rm, 16));
            rm = fmaxf(rm, __shfl_xor(rm, 32));
            float mnew  = fmaxf(mi_s, rm);
            float alpha = EXP2(mi_s - mnew);   // exp2(-inf)=0 on first tile
            mi_s = mnew;

            #pragma unroll
            for (int nc = 0; nc < 8; ++nc)
                #pragma unroll
                for (int r = 0; r < 4; ++r)
                    sacc[nc][r] = EXP2(sacc[nc][r] - mnew);  // masked -> 0

            float ts[8];
            #pragma unroll
            for (int nc = 0; nc < 8; ++nc)
                ts[nc] = (sacc[nc][0] + sacc[nc][1]) + (sacc[nc][2] + sacc[nc][3]);
            float asum = ((ts[0] + ts[1]) + (ts[2] + ts[3]))
                       + ((ts[4] + ts[5]) + (ts[6] + ts[7]));
            asum += __shfl_xor(asum, 16);
            asum += __shfl_xor(asum, 32);
            li_s = li_s * alpha + asum;

            // rescale O: output rows q*4+r live in lanes with m = q*4+r
            float ar[4];
            #pragma unroll
            for (int r = 0; r < 4; ++r) ar[r] = __shfl(alpha, q * 20 + r);
            #pragma unroll
            for (int nb = 0; nb < 4; ++nb)
                #pragma unroll
                for (int r = 0; r < 4; ++r) oacc[nb][r] *= ar[r];

            // pack P pairs to bf16 and route into PV A-fragments in-register.
            unsigned int u0[8], u1[8];
            #pragma unroll
            for (int nc = 0; nc < 8; ++nc) {
                u0[nc] = cvt_pk_bf16(sacc[nc][0], sacc[nc][1]);
                u1[nc] = cvt_pk_bf16(sacc[nc][2], sacc[nc][3]);
            }
            short8 pa[4];
            #pragma unroll
            for (int ck = 0; ck < 4; ++ck) {
                unsigned int x0 = u0[2 * ck], y0 = u0[2 * ck + 1];
                P32SWAP(x0, y0);
                P16SWAP(x0, y0);
                unsigned int x1 = u1[2 * ck], y1 = u1[2 * ck + 1];
                P32SWAP(x1, y1);
                P16SWAP(x1, y1);
                union { u32x4 u; short8 s; } uu;
                uu.u = (u32x4){x0, x1, y0, y1};
                pa[ck] = uu.s;
            }

            #pragma unroll
            for (int nb = 0; nb < 4; ++nb)
                #pragma unroll
                for (int ck = 0; ck < 4; ++ck) {
                    short8 vf = *(const short8*)&Vs[(nb * 16 + m) * VST + ck * 32 + q * 8];
                    oacc[nb] = MFMA16(pa[ck], vf, oacc[nb]);
                }
        }

        // epilogue: UNNORMALIZED partial store + (m,l) per row.
        // row (rowbase + m) state lives in all 4 q-copies; q==0 writes m/l.
        if (q == 0) {
            float* mlp = Ml + ((bh * 32 + qtile) * 2 + half) * 128;
            mlp[wave * 16 + m]      = mi_s;
            mlp[64 + wave * 16 + m] = li_s;
        }
        if (half == 0) {
            #pragma unroll
            for (int r = 0; r < 4; ++r) {
                int srowg = qtile * 64 + wave * 16 + q * 4 + r;
                #pragma unroll
                for (int nb = 0; nb < 4; ++nb)
                    ctx[(b * 2048 + srowg) * 1024 + h * 64 + nb * 16 + m] =
                        __float2bfloat16(oacc[nb][r]);
            }
        } else {
            #pragma unroll
            for (int r = 0; r < 4; ++r) {
                int srowl = wave * 16 + q * 4 + r;
                #pragma unroll
                for (int nb = 0; nb < 4; ++nb)
                    Op1[((bh * 32 + qtile) * 64 + srowl) * 64 + nb * 16 + m] =
                        __float2bfloat16(oacc[nb][r]);
            }
        }
        __syncthreads();
    }
}

// ---------------------------------------------------------------------------
// Kernel 2b: merge the two K-half partials per (bh, qtile).
// O = (O0*2^(m0-m) + O1*2^(m1-m)) / (l0*2^(m0-m) + l1*2^(m1-m)), m=max.
// grid = (32 qtiles, 32 bh), block = 256: thread = (row rr, 16-col seg).
// ---------------------------------------------------------------------------
__global__ __launch_bounds__(256) void flash_merge(
    bf16* __restrict__ ctx, const bf16* __restrict__ Op1,
    const float* __restrict__ Ml)
{
    const int qt = blockIdx.x, bh = blockIdx.y;
    const int b = bh >> 4, h = bh & 15;
    const int rr = threadIdx.x >> 2;
    const int cs = (threadIdx.x & 3) * 16;

    const float* mlp = Ml + (bh * 32 + qt) * 256;
    float m0 = mlp[rr],       l0 = mlp[64 + rr];
    float m1 = mlp[128 + rr], l1 = mlp[192 + rr];
    float mm = fmaxf(m0, m1);
    float w0 = EXP2(m0 - mm), w1 = EXP2(m1 - mm);
    float inv = 1.f / (l0 * w0 + l1 * w1);
    w0 *= inv; w1 *= inv;

    bf16* cp       = ctx + (b * 2048 + qt * 64 + rr) * 1024 + h * 64 + cs;
    const bf16* pp = Op1 + ((bh * 32 + qt) * 64 + rr) * 64 + cs;
    #pragma unroll
    for (int seg = 0; seg < 2; ++seg) {
        short8 a  = *(const short8*)(cp + seg * 8);
        short8 bb = *(const short8*)(pp + seg * 8);
        short8 o;
        #pragma unroll
        for (int j = 0; j < 8; ++j) {
            float fa = __bfloat162float(((const bf16*)&a)[j]);
            float fb = __bfloat162float(((const bf16*)&bb)[j]);
            bf16 hv = __float2bfloat16(fa * w0 + fb * w1);
            o[j] = *(short*)&hv;
        }
        *(short8*)(cp + seg * 8) = o;
    }
}

// ---------------------------------------------------------------------------
// Kernel 3: output projection, 128x128 tile. grid = (32, 8), block = 256.
// ---------------------------------------------------------------------------
__global__ __launch_bounds__(256, 1) void gemm_out(
    const bf16* __restrict__ A,
    const void* __restrict__ wor, const bf16* __restrict__ Woc,
    const void* __restrict__ xr,
    void* __restrict__ out)
{
    const bool f32in = inputs_are_fp32((const unsigned short*)xr);
    const bf16* W = f32in ? Woc : (const bf16*)wor;

    __shared__ __align__(16) short As[128 * 40];
    __shared__ __align__(16) short Bs[128 * 40];

    const int m0 = blockIdx.x * 128;
    const int n0 = blockIdx.y * 128;
    const int tid  = threadIdx.x;
    const int lane = tid & 63;
    const int wave = tid >> 6;
    const int wr = wave >> 1, wc = wave & 1;
    const int m = lane & 15, q = lane >> 4;
    const int srow = tid >> 2, sseg = tid & 3;

    const bf16* Ag = A + (m0 + srow) * 1024 + sseg * 8;
    const bf16* Bg = W + (n0 + srow) * 1024 + sseg * 8;

    f32x4 acc[4][4];
    #pragma unroll
    for (int mi = 0; mi < 4; ++mi)
        #pragma unroll
        for (int ni = 0; ni < 4; ++ni)
            acc[mi][ni] = (f32x4){0.f, 0.f, 0.f, 0.f};

    short8 pa0 = *(const short8*)(Ag);
    short8 pa1 = *(const short8*)(Ag + 64 * 1024);
    short8 pb0 = *(const short8*)(Bg);
    short8 pb1 = *(const short8*)(Bg + 64 * 1024);

    for (int k0 = 0; k0 < 1024; k0 += 32) {
        __syncthreads();
        *(short8*)&As[srow * 40 + sseg * 8]        = pa0;
        *(short8*)&As[(srow + 64) * 40 + sseg * 8] = pa1;
        *(short8*)&Bs[srow * 40 + sseg * 8]        = pb0;
        *(short8*)&Bs[(srow + 64) * 40 + sseg * 8] = pb1;
        __syncthreads();
        if (k0 + 32 < 1024) {
            pa0 = *(const short8*)(Ag + k0 + 32);
            pa1 = *(const short8*)(Ag + 64 * 1024 + k0 + 32);
            pb0 = *(const short8*)(Bg + k0 + 32);
            pb1 = *(const short8*)(Bg + 64 * 1024 + k0 + 32);
        }

        short8 af[4], bfr[4];
        #pragma unroll
        for (int mi = 0; mi < 4; ++mi)
            af[mi] = *(const short8*)&As[(wr * 64 + mi * 16 + m) * 40 + q * 8];
        #pragma unroll
        for (int ni = 0; ni < 4; ++ni)
            bfr[ni] = *(const short8*)&Bs[(wc * 64 + ni * 16 + m) * 40 + q * 8];
        #pragma unroll
        for (int mi = 0; mi < 4; ++mi)
            #pragma unroll
            for (int ni = 0; ni < 4; ++ni)
                acc[mi][ni] = MFMA16(af[mi], bfr[ni], acc[mi][ni]);
    }

    #pragma unroll
    for (int mi = 0; mi < 4; ++mi)
        #pragma unroll
        for (int ni = 0; ni < 4; ++ni)
            #pragma unroll
            for (int r = 0; r < 4; ++r) {
                int gm = m0 + wr * 64 + mi * 16 + q * 4 + r;
                int gn = n0 + wc * 64 + ni * 16 + m;
                int idx = gm * 1024 + gn;
                if (f32in) ((float*)out)[idx] = acc[mi][ni][r];
                else       ((bf16*)out)[idx]  = __float2bfloat16(acc[mi][ni][r]);
            }
}

// ---------------------------------------------------------------------------
extern "C" void kernel_launch(void* const* d_in, const int* in_sizes, int n_in,
                              void* d_out, int out_size, void* d_ws, size_t ws_size,
                              hipStream_t stream)
{
    const void* x_raw  = d_in[0];
    const void* Wq_raw = d_in[1];
    const void* Wk_raw = d_in[2];
    const void* Wv_raw = d_in[3];
    const void* Wo_raw = d_in[4];
    const int*  pos    = (const int*)d_in[5];

    char* ws = (char*)d_ws;
    bf16* Xc  = (bf16*)ws;                                    // 8 MB
    bf16* Wqc = (bf16*)(ws + 8388608);                        // 2 MB each
    bf16* Wkc = (bf16*)(ws + 8388608 + 2097152);
    bf16* Wvc = (bf16*)(ws + 8388608 + 2 * 2097152);
    bf16* Woc = (bf16*)(ws + 8388608 + 3 * 2097152);
    bf16* Qb  = (bf16*)(ws + 8388608 + 4 * 2097152);          // 8 MB each
    bf16* Kb  = Qb + 4194304;
    bf16* Vt  = Kb + 4194304;
    bf16* ctx = Vt + 4194304;
    float2* rtab = (float2*)(ctx + 4194304);                  // 512 KB

    // recycled (dead after gemm_qkv_rope): partial-O half1 over Xc (8 MB),
    // m/l array over Wqc (1 MB of its 2 MB).
    bf16*  Op1 = (bf16*)ws;
    float* Ml  = (float*)(ws + 8388608);

    rope_table<<<256, 256, 0, stream>>>(pos, rtab);
    convert_all<<<16384, 256, 0, stream>>>(
        x_raw, Wq_raw, Wk_raw, Wv_raw, Wo_raw,
        (unsigned int*)Xc, (unsigned int*)Wqc, (unsigned int*)Wkc,
        (unsigned int*)Wvc, (unsigned int*)Woc);

    gemm_qkv_rope<<<dim3(32, 24), 256, 0, stream>>>(
        x_raw, Wq_raw, Wk_raw, Wv_raw, Xc, Wqc, Wkc, Wvc, rtab, Qb, Kb, Vt);
    flash_attn<<<dim3(32, 16, 2), 256, 0, stream>>>(Qb, Kb, Vt, ctx, Op1, Ml);
    flash_merge<<<dim3(32, 32), 256, 0, stream>>>(ctx, Op1, Ml);
    gemm_out<<<dim3(32, 8), 256, 0, stream>>>(ctx, Wo_raw, Woc, x_raw, d_out);
}

// Round 5
// 193.046 us; speedup vs baseline: 1.0891x; 1.0891x over previous
//
#include <hip/hip_runtime.h>
#include <hip/hip_bf16.h>
#include <math.h>

typedef __hip_bfloat16 bf16;
typedef __attribute__((ext_vector_type(8))) short short8;
typedef __attribute__((ext_vector_type(4))) float f32x4;
typedef __attribute__((ext_vector_type(4))) unsigned int u32x4;

#define MFMA16(A, B, C) __builtin_amdgcn_mfma_f32_16x16x32_bf16((A), (B), (C), 0, 0, 0)
#define NEG_BIG (-1e30f)
#define EXP2(x) __builtin_amdgcn_exp2f(x)
// 0.125 (1/sqrt(d_k)) * log2(e): folded into Q at projection time -> scores in log2 domain
#define QSCALE 0.18033688011112042f

// two-register half-swaps (gfx950)
#define P32SWAP(a, b) asm("v_permlane32_swap_b32 %0, %1" : "+v"(a), "+v"(b))
#define P16SWAP(a, b) asm("v_permlane16_swap_b32 %0, %1" : "+v"(a), "+v"(b))

static __device__ __forceinline__ unsigned int cvt_pk_bf16(float lo, float hi) {
    unsigned int r;
    asm("v_cvt_pk_bf16_f32 %0, %1, %2" : "=v"(r) : "v"(lo), "v"(hi));
    return r;
}

// async global->LDS, 16B per lane; LDS dest is wave-uniform base + lane*16
static __device__ __forceinline__ void gload16(const bf16* g, void* l) {
    __builtin_amdgcn_global_load_lds(
        (const __attribute__((address_space(1))) void*)g,
        (__attribute__((address_space(3))) void*)l,
        16, 0, 0);
}

// fp32 -> bf16 round-to-nearest-even via bit ops
static __device__ __forceinline__ unsigned short f32_to_bf16_rne(float f) {
    unsigned int u = __float_as_uint(f);
    unsigned int rnd = 0x7FFFu + ((u >> 16) & 1u);
    return (unsigned short)((u + rnd) >> 16);
}

// In-kernel dtype detection (wave-uniform): scan first 64 shorts of x.
static __device__ __forceinline__ bool inputs_are_fp32(const unsigned short* x16) {
    int lane = threadIdx.x & 63;
    int e = (x16[lane] >> 7) & 0xFF;
    unsigned long long ball = __ballot(e >= 133);
    return __popcll(ball) >= 4;
}

// ---------------------------------------------------------------------------
// Kernel 0a: RoPE cos/sin table [s][p] float2, 2048 x 32 entries (512 KB).
// ---------------------------------------------------------------------------
__global__ __launch_bounds__(256) void rope_table(
    const int* __restrict__ pos, float2* __restrict__ tab)
{
    int i = blockIdx.x * 256 + threadIdx.x;   // 0..65535
    int s = i >> 5, p = i & 31;
    float freq = __expf((float)p * -0.28782313662425575f);
    float ang  = (float)pos[s] * freq;
    float sn, c;
    sincosf(ang, &sn, &c);
    tab[i] = make_float2(c, sn);
}

// ---------------------------------------------------------------------------
// Kernel 0b: canonical bf16 copies of all 5 inputs (fp32 path only).
// ---------------------------------------------------------------------------
__global__ __launch_bounds__(256) void convert_all(
    const void* __restrict__ xs, const void* __restrict__ wq,
    const void* __restrict__ wk, const void* __restrict__ wv,
    const void* __restrict__ wo,
    unsigned int* __restrict__ Xc, unsigned int* __restrict__ Wqc,
    unsigned int* __restrict__ Wkc, unsigned int* __restrict__ Wvc,
    unsigned int* __restrict__ Woc)
{
    if (!inputs_are_fp32((const unsigned short*)xs)) return;
    int i = blockIdx.x * 256 + threadIdx.x;  // 0 .. 4194303
    const float* src;
    unsigned int* dst;
    int off;
    if (i < 2097152) { src = (const float*)xs; dst = Xc; off = i; }
    else {
        int j = i - 2097152;
        int t = j >> 19;          // 0..3
        off = j & 524287;
        src = (const float*)((t == 0) ? wq : (t == 1) ? wk : (t == 2) ? wv : wo);
        dst = (t == 0) ? Wqc : (t == 1) ? Wkc : (t == 2) ? Wvc : Woc;
    }
    unsigned int lo = f32_to_bf16_rne(src[2 * off]);
    unsigned int hi = f32_to_bf16_rne(src[2 * off + 1]);
    dst[off] = (hi << 16) | lo;
}

// ---------------------------------------------------------------------------
// Kernel 1: QKV projection GEMM, 128x128 tile, BK=32.
// Round-4: m97-class staging — double-buffered LINEAR LDS [128][32] per
// operand, global_load_lds width=16 (no reg staging, no ds_write, no
// address VALU), ONE barrier per K-step. gload_lds demands linear dest,
// so bank-decorrelation is done by XOR-swizzling the k-segment on the
// GLOBAL source ((l&3)^((l>>3)&3)) and applying the same XOR on the
// fragment read (q ^ ((m>>1)&3)) -> <=2-way LDS aliasing (free).
// grid = (32 m-tiles, 24 = 3 weights x 8 n-tiles), block = 256 (2x2 waves).
// Q,K: RoPE-table epilogue [b,h,s,d]. V: LDS-transposed [b,h,d,s].
// Q pre-scaled by 0.125*log2(e) -> flash softmax in exp2 domain.
// ---------------------------------------------------------------------------
__global__ __launch_bounds__(256, 1) void gemm_qkv_rope(
    const void* __restrict__ xr,
    const void* __restrict__ wqr, const void* __restrict__ wkr,
    const void* __restrict__ wvr,
    const bf16* __restrict__ Xc,
    const bf16* __restrict__ Wqc, const bf16* __restrict__ Wkc,
    const bf16* __restrict__ Wvc,
    const float2* __restrict__ rtab,
    bf16* __restrict__ Qb, bf16* __restrict__ Kb, bf16* __restrict__ Vt)
{
    const bool f32in = inputs_are_fp32((const unsigned short*)xr);
    const bf16* X = f32in ? Xc : (const bf16*)xr;

    // union: dbuf staging (2 x (A[128][32]+B[128][32]) = 16384 shorts)
    //        vs V-transpose tile (128x132 = 16896 shorts)
    __shared__ __align__(16) short smem[128 * 132];   // 33792 B

    const int m0   = blockIdx.x * 128;
    const int wsel = blockIdx.y >> 3;            // 0=Q, 1=K, 2=V
    const int n0   = (blockIdx.y & 7) * 128;
    const bf16* W  = (wsel == 0) ? (f32in ? Wqc : (const bf16*)wqr)
                   : (wsel == 1) ? (f32in ? Wkc : (const bf16*)wkr)
                                 : (f32in ? Wvc : (const bf16*)wvr);

    const int tid  = threadIdx.x;
    const int lane = tid & 63;
    const int wave = tid >> 6;
    const int wr   = wave >> 1, wc = wave & 1;   // 2x2 waves, each 64x64
    const int m    = lane & 15;
    const int q    = lane >> 4;

    // staging: wave covers rows wave*32..+31; lane row = +lane>>2, phys slot
    // lane&3 holds logical k-seg (lane&3)^((lane>>3)&3)  [= (row>>1)&3]
    const int stgrow = wave * 32 + (lane >> 2);
    const int ksegsh = (((lane & 3) ^ ((lane >> 3) & 3)) * 8);   // shorts
    const bf16* Ag = X + (m0 + stgrow) * 1024 + ksegsh;
    const bf16* Bg = W + (n0 + stgrow) * 1024 + ksegsh;
    char* const smemB = (char*)smem;
    // fragment-read swizzle: logical slot q lives at phys q ^ ((row>>1)&3),
    // and (row>>1)&3 == (m>>1)&3 for all row = {wr,wc}*64 + {mi,ni}*16 + m.
    const int aoff = ((q ^ ((m >> 1) & 3)) * 8);   // shorts within 32-short row

    f32x4 acc[4][4];
    #pragma unroll
    for (int mi = 0; mi < 4; ++mi)
        #pragma unroll
        for (int ni = 0; ni < 4; ++ni)
            acc[mi][ni] = (f32x4){0.f, 0.f, 0.f, 0.f};

    // prologue: stage tile 0 into buffer 0
    {
        char* la = smemB + wave * 2048;           // A buf0 + wave rows
        char* lb = smemB + 8192 + wave * 2048;    // B buf0
        gload16(Ag,            la);
        gload16(Ag + 16 * 1024, la + 1024);       // +16 rows
        gload16(Bg,            lb);
        gload16(Bg + 16 * 1024, lb + 1024);
    }

    for (int k0 = 0; k0 < 1024; k0 += 32) {
        const int bs = (k0 >> 5) & 1;
        __syncthreads();                           // buf[bs] landed (vmcnt drain)
        if (k0 + 32 < 1024) {                      // stage next into buf[bs^1]
            char* la = smemB + (bs ^ 1) * 16384 + wave * 2048;
            char* lb = la + 8192;
            gload16(Ag + (k0 + 32),             la);
            gload16(Ag + (k0 + 32) + 16 * 1024, la + 1024);
            gload16(Bg + (k0 + 32),             lb);
            gload16(Bg + (k0 + 32) + 16 * 1024, lb + 1024);
        }

        const short* As = smem + bs * 8192;        // shorts
        const short* Bs = As + 4096;
        short8 af[4], bfr[4];
        #pragma unroll
        for (int mi = 0; mi < 4; ++mi)
            af[mi] = *(const short8*)&As[(wr * 64 + mi * 16 + m) * 32 + aoff];
        #pragma unroll
        for (int ni = 0; ni < 4; ++ni)
            bfr[ni] = *(const short8*)&Bs[(wc * 64 + ni * 16 + m) * 32 + aoff];
        #pragma unroll
        for (int mi = 0; mi < 4; ++mi)
            #pragma unroll
            for (int ni = 0; ni < 4; ++ni)
                acc[mi][ni] = MFMA16(af[mi], bfr[ni], acc[mi][ni]);
    }

    const int bb  = m0 >> 11;
    const int s0  = m0 & 2047;
    const int hh0 = n0 >> 6;          // first of 2 heads in this n-tile

    if (wsel < 2) {
        bf16* dstb = (wsel == 0) ? Qb : Kb;
        const float sc = (wsel == 0) ? QSCALE : 1.0f;
        #pragma unroll
        for (int mi = 0; mi < 4; ++mi)
            #pragma unroll
            for (int ni = 0; ni < 4; ++ni)
                #pragma unroll
                for (int r = 0; r < 4; ++r) {
                    int s  = s0 + wr * 64 + mi * 16 + q * 4 + r;
                    int gn = n0 + wc * 64 + ni * 16 + m;
                    int hh = gn >> 6, d = gn & 63;
                    float v = acc[mi][ni][r];
                    float partner = __shfl_xor(v, 1);
                    float2 cs = rtab[s * 32 + (d >> 1)];
                    float outv = ((d & 1) == 0) ? (cs.x * v - cs.y * partner)
                                                : (cs.y * partner + cs.x * v);
                    dstb[((bb * 16 + hh) * 2048 + s) * 64 + d] =
                        __float2bfloat16(outv * sc);
                }
    } else {
        __syncthreads();   // all staging reads done before alias overwrite
        #pragma unroll
        for (int mi = 0; mi < 4; ++mi)
            #pragma unroll
            for (int ni = 0; ni < 4; ++ni)
                #pragma unroll
                for (int r = 0; r < 4; ++r) {
                    int ls = wr * 64 + mi * 16 + q * 4 + r;   // local s 0..127
                    int ld = wc * 64 + ni * 16 + m;           // local d 0..127
                    bf16 hv = __float2bfloat16(acc[mi][ni][r]);
                    smem[ld * 132 + ls] = *(short*)&hv;
                }
        __syncthreads();
        int dd = tid >> 1;            // 0..127: head hh0 + (dd>>6), d = dd&63
        int half = tid & 1;
        bf16* vrow = Vt + ((bb * 16 + hh0 + (dd >> 6)) * 64 + (dd & 63)) * 2048
                        + s0 + half * 64;
        #pragma unroll
        for (int j = 0; j < 8; ++j)
            *(short8*)(vrow + j * 8) =
                *(const short8*)&smem[dd * 132 + half * 64 + j * 8];
    }
}

// ---------------------------------------------------------------------------
// Kernel 2: causal flash attention, paired-qtile (512 balanced blocks, 17
// serial K-iterations each) — the round-2 proven version (51.3 us).
// Swapped QK^T (mfma(K,Q)): lane owns one softmax row; in-register P
// routing via cvt_pk + permlane32/16_swap; exp2-domain softmax.
// ---------------------------------------------------------------------------
#define KST 72
#define VST 136

__global__ __launch_bounds__(256) void flash_attn(
    const bf16* __restrict__ Qb, const bf16* __restrict__ Kb,
    const bf16* __restrict__ Vt, bf16* __restrict__ ctx)
{
    const int pair = blockIdx.x;      // 0..15
    const int h = blockIdx.y, b = blockIdx.z;
    const int bh = b * 16 + h;

    __shared__ __align__(16) short Ks[128 * KST];
    __shared__ __align__(16) short Vs[64 * VST];

    const int tid  = threadIdx.x;
    const int lane = tid & 63;
    const int wave = tid >> 6;
    const int m = lane & 15;
    const int q = lane >> 4;

    const int krow = tid >> 1;
    const int kseg = (tid & 1) * 32;
    const int ksw  = ((krow >> 3) & 3) << 3;   // staging swizzle (shorts)
    const int vrow = tid >> 2;
    const int vseg = (tid & 3) * 32;

    const bf16* Kg = Kb + bh * 2048 * 64 + krow * 64   + kseg;
    const bf16* Vg = Vt + bh * 64 * 2048 + vrow * 2048 + vseg;

    for (int part = 0; part < 2; ++part) {
        const int qtile = (part == 0) ? pair : 31 - pair;
        const int nk2 = (qtile + 2) >> 1;
        const int rowbase = qtile * 64 + wave * 16;

        const bf16* Qp = Qb + (bh * 2048 + rowbase + m) * 64;
        short8 qf0 = *(const short8*)(Qp + q * 8);
        short8 qf1 = *(const short8*)(Qp + 32 + q * 8);

        f32x4 oacc[4];
        #pragma unroll
        for (int nb = 0; nb < 4; ++nb) oacc[nb] = (f32x4){0.f, 0.f, 0.f, 0.f};
        float mi_s = NEG_BIG, li_s = 0.f;   // per-lane softmax row = rowbase + m

        short8 kr[4], vr[4];
        #pragma unroll
        for (int j = 0; j < 4; ++j) {
            kr[j] = *(const short8*)(Kg + j * 8);
            vr[j] = *(const short8*)(Vg + j * 8);
        }

        for (int kt2 = 0; kt2 < nk2; ++kt2) {
            __syncthreads();
            #pragma unroll
            for (int j = 0; j < 4; ++j) {
                *(short8*)&Ks[krow * KST + ((kseg + j * 8) ^ ksw)] = kr[j];
                *(short8*)&Vs[vrow * VST + vseg + j * 8] = vr[j];
            }
            __syncthreads();

            if (kt2 + 1 < nk2) {
                #pragma unroll
                for (int j = 0; j < 4; ++j) {
                    kr[j] = *(const short8*)(Kg + (kt2 + 1) * 8192 + j * 8);
                    vr[j] = *(const short8*)(Vg + (kt2 + 1) * 128  + j * 8);
                }
            }

            // swapped QK^T: S[q-row = m][key = kt2*128 + nc*16 + q*4 + r]
            f32x4 sacc[8];
            #pragma unroll
            for (int nc = 0; nc < 8; ++nc) {
                int row = nc * 16 + m;
                int sw  = ((row >> 3) & 3) << 3;
                const short* kp = &Ks[row * KST];
                short8 kf0 = *(const short8*)&kp[(q * 8) ^ sw];
                short8 kf1 = *(const short8*)&kp[32 + ((q * 8) ^ sw)];
                f32x4 z = {0.f, 0.f, 0.f, 0.f};
                z = MFMA16(kf0, qf0, z);
                z = MFMA16(kf1, qf1, z);
                sacc[nc] = z;
            }

            // causal mask (log2-domain scores; scale folded into Q)
            if (kt2 * 128 + 127 > rowbase) {
                int rowg = rowbase + m;
                #pragma unroll
                for (int nc = 0; nc < 8; ++nc)
                    #pragma unroll
                    for (int r = 0; r < 4; ++r) {
                        int col = kt2 * 128 + nc * 16 + q * 4 + r;
                        if (col > rowg) sacc[nc][r] = NEG_BIG;
                    }
            }

            // in-lane tree max + cross-q butterfly (lanes m,q=0..3 share row m)
            float tm[8];
            #pragma unroll
            for (int nc = 0; nc < 8; ++nc)
                tm[nc] = fmaxf(fmaxf(sacc[nc][0], sacc[nc][1]),
                               fmaxf(sacc[nc][2], sacc[nc][3]));
            float rm = fmaxf(fmaxf(fmaxf(tm[0], tm[1]), fmaxf(tm[2], tm[3])),
                             fmaxf(fmaxf(tm[4], tm[5]), fmaxf(tm[6], tm[7])));
            rm = fmaxf(rm, __shfl_xor(rm, 16));
            rm = fmaxf(rm, __shfl_xor(rm, 32));
            float mnew  = fmaxf(mi_s, rm);
            float alpha = EXP2(mi_s - mnew);   // exp2(-inf)=0 on first tile
            mi_s = mnew;

            #pragma unroll
            for (int nc = 0; nc < 8; ++nc)
                #pragma unroll
                for (int r = 0; r < 4; ++r)
                    sacc[nc][r] = EXP2(sacc[nc][r] - mnew);  // masked -> 0

            float ts[8];
            #pragma unroll
            for (int nc = 0; nc < 8; ++nc)
                ts[nc] = (sacc[nc][0] + sacc[nc][1]) + (sacc[nc][2] + sacc[nc][3]);
            float asum = ((ts[0] + ts[1]) + (ts[2] + ts[3]))
                       + ((ts[4] + ts[5]) + (ts[6] + ts[7]));
            asum += __shfl_xor(asum, 16);
            asum += __shfl_xor(asum, 32);
            li_s = li_s * alpha + asum;

            // rescale O: output rows q*4+r live in lanes with m = q*4+r
            float ar[4];
            #pragma unroll
            for (int r = 0; r < 4; ++r) ar[r] = __shfl(alpha, q * 20 + r);
            #pragma unroll
            for (int nb = 0; nb < 4; ++nb)
                #pragma unroll
                for (int r = 0; r < 4; ++r) oacc[nb][r] *= ar[r];

            // pack P pairs to bf16 and route into PV A-fragments in-register.
            unsigned int u0[8], u1[8];
            #pragma unroll
            for (int nc = 0; nc < 8; ++nc) {
                u0[nc] = cvt_pk_bf16(sacc[nc][0], sacc[nc][1]);
                u1[nc] = cvt_pk_bf16(sacc[nc][2], sacc[nc][3]);
            }
            short8 pa[4];
            #pragma unroll
            for (int ck = 0; ck < 4; ++ck) {
                unsigned int x0 = u0[2 * ck], y0 = u0[2 * ck + 1];
                P32SWAP(x0, y0);
                P16SWAP(x0, y0);
                unsigned int x1 = u1[2 * ck], y1 = u1[2 * ck + 1];
                P32SWAP(x1, y1);
                P16SWAP(x1, y1);
                union { u32x4 u; short8 s; } uu;
                uu.u = (u32x4){x0, x1, y0, y1};
                pa[ck] = uu.s;
            }

            #pragma unroll
            for (int nb = 0; nb < 4; ++nb)
                #pragma unroll
                for (int ck = 0; ck < 4; ++ck) {
                    short8 vf = *(const short8*)&Vs[(nb * 16 + m) * VST + ck * 32 + q * 8];
                    oacc[nb] = MFMA16(pa[ck], vf, oacc[nb]);
                }
        }

        // epilogue: li for output row q*4+r lives in lanes m = q*4+r
        float lr[4];
        #pragma unroll
        for (int r = 0; r < 4; ++r) lr[r] = __shfl(li_s, q * 20 + r);
        #pragma unroll
        for (int r = 0; r < 4; ++r) {
            float inv = 1.f / lr[r];
            int srowg = qtile * 64 + wave * 16 + q * 4 + r;
            #pragma unroll
            for (int nb = 0; nb < 4; ++nb)
                ctx[(b * 2048 + srowg) * 1024 + h * 64 + nb * 16 + m] =
                    __float2bfloat16(oacc[nb][r] * inv);
        }
        __syncthreads();
    }
}

// ---------------------------------------------------------------------------
// Kernel 3: output projection, 128x128 tile — same m97-class staging as
// kernel 1 (dbuf linear LDS + global_load_lds + source-side swizzle).
// grid = (32, 8), block = 256.
// ---------------------------------------------------------------------------
__global__ __launch_bounds__(256, 1) void gemm_out(
    const bf16* __restrict__ A,
    const void* __restrict__ wor, const bf16* __restrict__ Woc,
    const void* __restrict__ xr,
    void* __restrict__ out)
{
    const bool f32in = inputs_are_fp32((const unsigned short*)xr);
    const bf16* W = f32in ? Woc : (const bf16*)wor;

    __shared__ __align__(16) short smem[16384];   // 2 x (A+B) dbuf, 32768 B

    const int m0 = blockIdx.x * 128;
    const int n0 = blockIdx.y * 128;
    const int tid  = threadIdx.x;
    const int lane = tid & 63;
    const int wave = tid >> 6;
    const int wr = wave >> 1, wc = wave & 1;
    const int m = lane & 15, q = lane >> 4;

    const int stgrow = wave * 32 + (lane >> 2);
    const int ksegsh = (((lane & 3) ^ ((lane >> 3) & 3)) * 8);
    const bf16* Ag = A + (m0 + stgrow) * 1024 + ksegsh;
    const bf16* Bg = W + (n0 + stgrow) * 1024 + ksegsh;
    char* const smemB = (char*)smem;
    const int aoff = ((q ^ ((m >> 1) & 3)) * 8);

    f32x4 acc[4][4];
    #pragma unroll
    for (int mi = 0; mi < 4; ++mi)
        #pragma unroll
        for (int ni = 0; ni < 4; ++ni)
            acc[mi][ni] = (f32x4){0.f, 0.f, 0.f, 0.f};

    {
        char* la = smemB + wave * 2048;
        char* lb = smemB + 8192 + wave * 2048;
        gload16(Ag,            la);
        gload16(Ag + 16 * 1024, la + 1024);
        gload16(Bg,            lb);
        gload16(Bg + 16 * 1024, lb + 1024);
    }

    for (int k0 = 0; k0 < 1024; k0 += 32) {
        const int bs = (k0 >> 5) & 1;
        __syncthreads();
        if (k0 + 32 < 1024) {
            char* la = smemB + (bs ^ 1) * 16384 + wave * 2048;
            char* lb = la + 8192;
            gload16(Ag + (k0 + 32),             la);
            gload16(Ag + (k0 + 32) + 16 * 1024, la + 1024);
            gload16(Bg + (k0 + 32),             lb);
            gload16(Bg + (k0 + 32) + 16 * 1024, lb + 1024);
        }

        const short* As = smem + bs * 8192;
        const short* Bs = As + 4096;
        short8 af[4], bfr[4];
        #pragma unroll
        for (int mi = 0; mi < 4; ++mi)
            af[mi] = *(const short8*)&As[(wr * 64 + mi * 16 + m) * 32 + aoff];
        #pragma unroll
        for (int ni = 0; ni < 4; ++ni)
            bfr[ni] = *(const short8*)&Bs[(wc * 64 + ni * 16 + m) * 32 + aoff];
        #pragma unroll
        for (int mi = 0; mi < 4; ++mi)
            #pragma unroll
            for (int ni = 0; ni < 4; ++ni)
                acc[mi][ni] = MFMA16(af[mi], bfr[ni], acc[mi][ni]);
    }

    #pragma unroll
    for (int mi = 0; mi < 4; ++mi)
        #pragma unroll
        for (int ni = 0; ni < 4; ++ni)
            #pragma unroll
            for (int r = 0; r < 4; ++r) {
                int gm = m0 + wr * 64 + mi * 16 + q * 4 + r;
                int gn = n0 + wc * 64 + ni * 16 + m;
                int idx = gm * 1024 + gn;
                if (f32in) ((float*)out)[idx] = acc[mi][ni][r];
                else       ((bf16*)out)[idx]  = __float2bfloat16(acc[mi][ni][r]);
            }
}

// ---------------------------------------------------------------------------
extern "C" void kernel_launch(void* const* d_in, const int* in_sizes, int n_in,
                              void* d_out, int out_size, void* d_ws, size_t ws_size,
                              hipStream_t stream)
{
    const void* x_raw  = d_in[0];
    const void* Wq_raw = d_in[1];
    const void* Wk_raw = d_in[2];
    const void* Wv_raw = d_in[3];
    const void* Wo_raw = d_in[4];
    const int*  pos    = (const int*)d_in[5];

    char* ws = (char*)d_ws;
    bf16* Xc  = (bf16*)ws;                                    // 8 MB
    bf16* Wqc = (bf16*)(ws + 8388608);                        // 2 MB each
    bf16* Wkc = (bf16*)(ws + 8388608 + 2097152);
    bf16* Wvc = (bf16*)(ws + 8388608 + 2 * 2097152);
    bf16* Woc = (bf16*)(ws + 8388608 + 3 * 2097152);
    bf16* Qb  = (bf16*)(ws + 8388608 + 4 * 2097152);          // 8 MB each
    bf16* Kb  = Qb + 4194304;
    bf16* Vt  = Kb + 4194304;
    bf16* ctx = Vt + 4194304;
    float2* rtab = (float2*)(ctx + 4194304);                  // 512 KB

    rope_table<<<256, 256, 0, stream>>>(pos, rtab);
    convert_all<<<16384, 256, 0, stream>>>(
        x_raw, Wq_raw, Wk_raw, Wv_raw, Wo_raw,
        (unsigned int*)Xc, (unsigned int*)Wqc, (unsigned int*)Wkc,
        (unsigned int*)Wvc, (unsigned int*)Woc);

    gemm_qkv_rope<<<dim3(32, 24), 256, 0, stream>>>(
        x_raw, Wq_raw, Wk_raw, Wv_raw, Xc, Wqc, Wkc, Wvc, rtab, Qb, Kb, Vt);
    flash_attn<<<dim3(16, 16, 2), 256, 0, stream>>>(Qb, Kb, Vt, ctx);
    gemm_out<<<dim3(32, 8), 256, 0, stream>>>(ctx, Wo_raw, Woc, x_raw, d_out);
}